// Round 2
// 536.720 us; speedup vs baseline: 1.0064x; 1.0064x over previous
//
#include <hip/hip_runtime.h>

// Sizes (compile-time constants from the reference)
#define SEQ_LEN 2048
#define EMBD 1024
#define VOCAB 32000
#define RANK 8
#define N_ROWS (2 * SEQ_LEN)      // 4096 token rows (b*T flattened)
#define T_TILE 64                 // token rows per proj block (B-register reuse)
#define V4_PER_ROW (VOCAB / 4)    // 8000 float4 per row

// Native vector type: __builtin_nontemporal_store requires a scalar or
// native vector type, not HIP's float4 class. Same 16B layout.
typedef float v4f __attribute__((ext_vector_type(4)));

// ---------------------------------------------------------------------------
// Kernel 1: low[row][r] = alpha * sum_e hidden[row][e] * A[bucket(t)][e][r]
// One block (256 threads) per token row. Each thread covers 4 consecutive e.
// Near its memory/latency floor (~15-20 us); unchanged this round.
// ---------------------------------------------------------------------------
__global__ __launch_bounds__(256) void low_kernel(const float* __restrict__ hidden,
                                                  const float* __restrict__ A,
                                                  const float* __restrict__ alpha_p,
                                                  float* __restrict__ low) {
    const int row = blockIdx.x;            // 0..4095
    const int t = row & (SEQ_LEN - 1);
    const int bucket = t >> 7;             // t / 128, already in [0,15]
    const int tid = threadIdx.x;
    const float alpha = alpha_p[0];

    const float* h  = hidden + (size_t)row * EMBD;
    const float* Ab = A + (size_t)bucket * EMBD * RANK;

    float acc[RANK];
#pragma unroll
    for (int r = 0; r < RANK; ++r) acc[r] = 0.f;

    const int e0 = tid * 4;                // 256 threads * 4 = 1024 elements
    const float4 hv = *reinterpret_cast<const float4*>(h + e0);
#pragma unroll
    for (int j = 0; j < 4; ++j) {
        const float hval = (&hv.x)[j];
        const float* Ar = Ab + (size_t)(e0 + j) * RANK;   // 8 contiguous floats
        const float4 a0 = *reinterpret_cast<const float4*>(Ar);
        const float4 a1 = *reinterpret_cast<const float4*>(Ar + 4);
        acc[0] += hval * a0.x; acc[1] += hval * a0.y;
        acc[2] += hval * a0.z; acc[3] += hval * a0.w;
        acc[4] += hval * a1.x; acc[5] += hval * a1.y;
        acc[6] += hval * a1.z; acc[7] += hval * a1.w;
    }

    // wave-64 butterfly reduce each rank accumulator
#pragma unroll
    for (int r = 0; r < RANK; ++r) {
#pragma unroll
        for (int off = 32; off > 0; off >>= 1)
            acc[r] += __shfl_down(acc[r], off, 64);
    }

    __shared__ float partial[4][RANK];
    const int wave = tid >> 6;
    const int lane = tid & 63;
    if (lane == 0) {
#pragma unroll
        for (int r = 0; r < RANK; ++r) partial[wave][r] = acc[r];
    }
    __syncthreads();
    if (tid < RANK) {
        const float s = partial[0][tid] + partial[1][tid] + partial[2][tid] + partial[3][tid];
        low[(size_t)row * RANK + tid] = alpha * s;
    }
}

// ---------------------------------------------------------------------------
// Kernel 2: out[row][v] = sum_r low[row][r] * B[r][v]   (alpha already folded)
// Each thread owns one float4 of v, keeps B[r][v..v+3] (8 float4 = 32 VGPR)
// in registers, reused across T_TILE=64 token rows -> B L2 traffic 64 MB
// (was 512 MB at T_TILE=8). Output written with NONTEMPORAL stores: the
// 524 MB write-once stream must not allocate in the 4 MB/XCD L2, or it
// evicts B ~16x over and throttles the write-back path.
// Grid (32, 64) = 2048 blocks = 8 blocks/CU: one full occupancy round.
// ---------------------------------------------------------------------------
__global__ __launch_bounds__(256) void proj_kernel(const float* __restrict__ low,
                                                   const float* __restrict__ B,
                                                   float* __restrict__ out) {
    const int v4 = blockIdx.x * 256 + threadIdx.x;   // float4 index within row
    const int row0 = blockIdx.y * T_TILE;            // first of 64 token rows

    __shared__ float slow[T_TILE * RANK];            // 512 floats = 2 KB
    for (int i = threadIdx.x; i < T_TILE * RANK; i += 256)
        slow[i] = low[(size_t)row0 * RANK + i];
    __syncthreads();

    if (v4 >= V4_PER_ROW) return;                    // only 64/256 idle in last x-block
    const int v = v4 * 4;

    float4 b[RANK];
#pragma unroll
    for (int r = 0; r < RANK; ++r)
        b[r] = *reinterpret_cast<const float4*>(B + (size_t)r * VOCAB + v);

    const float4* slow4 = reinterpret_cast<const float4*>(slow);
    float* outp = out + (size_t)row0 * VOCAB + v;

#pragma unroll 8
    for (int tt = 0; tt < T_TILE; ++tt) {
        // same-address LDS broadcast, 2x ds_read_b128 per row
        const float4 l0 = slow4[tt * 2];             // ranks 0..3
        const float4 l1 = slow4[tt * 2 + 1];         // ranks 4..7
        v4f o;
        o.x = l0.x * b[0].x + l0.y * b[1].x + l0.z * b[2].x + l0.w * b[3].x
            + l1.x * b[4].x + l1.y * b[5].x + l1.z * b[6].x + l1.w * b[7].x;
        o.y = l0.x * b[0].y + l0.y * b[1].y + l0.z * b[2].y + l0.w * b[3].y
            + l1.x * b[4].y + l1.y * b[5].y + l1.z * b[6].y + l1.w * b[7].y;
        o.z = l0.x * b[0].z + l0.y * b[1].z + l0.z * b[2].z + l0.w * b[3].z
            + l1.x * b[4].z + l1.y * b[5].z + l1.z * b[6].z + l1.w * b[7].z;
        o.w = l0.x * b[0].w + l0.y * b[1].w + l0.z * b[2].w + l0.w * b[3].w
            + l1.x * b[4].w + l1.y * b[5].w + l1.z * b[6].w + l1.w * b[7].w;
        __builtin_nontemporal_store(o, reinterpret_cast<v4f*>(outp));
        outp += VOCAB;
    }
}

extern "C" void kernel_launch(void* const* d_in, const int* in_sizes, int n_in,
                              void* d_out, int out_size, void* d_ws, size_t ws_size,
                              hipStream_t stream) {
    const float* hidden = (const float*)d_in[0];   // (2, 2048, 1024)
    const float* A      = (const float*)d_in[1];   // (16, 1024, 8)
    const float* B      = (const float*)d_in[2];   // (8, 32000)
    const float* alpha  = (const float*)d_in[3];   // scalar
    float* out = (float*)d_out;                    // (2, 2048, 32000)
    float* low = (float*)d_ws;                     // 4096 * 8 floats = 128 KB

    low_kernel<<<N_ROWS, 256, 0, stream>>>(hidden, A, alpha, low);

    dim3 grid((V4_PER_ROW + 255) / 256, N_ROWS / T_TILE);  // (32, 64)
    proj_kernel<<<grid, 256, 0, stream>>>(low, B, out);
}